// Round 1
// baseline (144.608 us; speedup 1.0000x reference)
//
#include <hip/hip_runtime.h>
#include <stdint.h>

#define NBL 8
#define MBS 512   // rows per blade
#define CIN 1024  // K per blade block
#define UQ  1024  // output cols per blade

// sigma[i][k]: j such that blade_i * blade_j = sign * blade_k ; sg[i][k] = sign
__device__ __constant__ int c_sigma[8][8] = {
  {0,1,2,3,4,5,6,7},
  {1,0,4,5,2,3,7,6},
  {2,4,0,6,1,7,3,5},
  {3,5,6,0,7,1,2,4},
  {4,2,1,7,0,6,5,3},
  {5,3,7,1,6,0,4,2},
  {6,7,3,2,5,4,0,1},
  {7,6,5,4,3,2,1,0},
};
__device__ __constant__ int c_sg[8][8] = {
  { 1, 1, 1, 1, 1, 1, 1, 1},
  { 1, 1, 1, 1, 1, 1, 1, 1},
  { 1,-1, 1, 1,-1,-1, 1,-1},
  { 1,-1,-1, 1, 1,-1,-1, 1},
  {-1, 1,-1,-1, 1, 1,-1, 1},
  {-1, 1, 1,-1,-1, 1, 1,-1},
  {-1,-1, 1,-1, 1,-1, 1, 1},
  {-1,-1, 1,-1, 1,-1, 1, 1},
};

typedef short bf16x8 __attribute__((ext_vector_type(8)));
typedef float f32x4 __attribute__((ext_vector_type(4)));

__device__ __forceinline__ uint32_t f2bf(float f) {
  uint32_t u = __float_as_uint(f);
  return (u + 0x7fffu + ((u >> 16) & 1u)) >> 16;  // RNE
}
__device__ __forceinline__ uint32_t pk2(float lo, float hi) {
  return f2bf(lo) | (f2bf(hi) << 16);
}

// x (4096x1024 f32) -> X+ bf16 and X- bf16 (sign flip = xor 0x8000, RNE-symmetric)
__global__ void cvt_x_kernel(const float4* __restrict__ x,
                             uint4* __restrict__ xp, uint4* __restrict__ xn) {
  int idx = blockIdx.x * blockDim.x + threadIdx.x;  // 524288 threads, 8 floats each
  float4 a = x[2 * idx];
  float4 b = x[2 * idx + 1];
  uint4 p;
  p.x = pk2(a.x, a.y); p.y = pk2(a.z, a.w);
  p.z = pk2(b.x, b.y); p.w = pk2(b.z, b.w);
  uint4 n;
  n.x = p.x ^ 0x80008000u; n.y = p.y ^ 0x80008000u;
  n.z = p.z ^ 0x80008000u; n.w = p.w ^ 0x80008000u;
  xp[idx] = p;
  xn[idx] = n;
}

// W [1024][8192] f32 -> Wt [8192][1024] bf16 (transpose so B-tiles are K-contiguous)
__global__ void cvt_w_kernel(const float* __restrict__ w, uint16_t* __restrict__ wt) {
  __shared__ float tile[32][33];
  int tx = threadIdx.x & 31, ty = threadIdx.x >> 5;  // 32x8
  int n0 = blockIdx.x * 32;   // 0..8191 over n
  int c0 = blockIdx.y * 32;   // 0..1023 over c
#pragma unroll
  for (int r = 0; r < 4; ++r) {
    int c = c0 + ty + r * 8;
    tile[ty + r * 8][tx] = w[(size_t)c * 8192 + n0 + tx];
  }
  __syncthreads();
#pragma unroll
  for (int r = 0; r < 4; ++r) {
    int n = n0 + ty + r * 8;
    wt[(size_t)n * 1024 + c0 + tx] = (uint16_t)f2bf(tile[tx][ty + r * 8]);
  }
}

// Main GEMM: per block (k, mt, ut): C_k[mt*128..+128, ut*128..+128] =
//   sum over K=8192 (8 i-blocks x 1024) of Xs_i[...] @ Wt[sigma(i,k)...]^T
__global__ __launch_bounds__(256, 1) void ga_gemm(
    const uint16_t* __restrict__ xp, const uint16_t* __restrict__ xn,
    const uint16_t* __restrict__ wt, const float* __restrict__ bias,
    float* __restrict__ out) {
  __shared__ uint16_t lds[2][2][128 * 64];  // [buf][A/B][128 rows][64 k] = 64 KB

  const int tid  = threadIdx.x;
  const int bid  = blockIdx.x;
  const int k    = bid >> 5;
  const int mt   = (bid >> 3) & 3;
  const int ut   = bid & 7;
  const int lane = tid & 63;
  const int wid  = tid >> 6;
  const int wr   = wid >> 1, wc = wid & 1;  // 2x2 waves, each 64x64 out

  f32x4 acc[4][4];
  const f32x4 z = {0.f, 0.f, 0.f, 0.f};
#pragma unroll
  for (int a = 0; a < 4; ++a)
#pragma unroll
    for (int b = 0; b < 4; ++b) acc[a][b] = z;

  auto stage = [&](int t, int buf) {
    const int i  = t >> 4;             // i-block (K block of 1024)
    const int c0 = (t & 15) << 6;      // k offset within block
    const uint16_t* ga = ((c_sg[i][k] > 0) ? xp : xn) +
                         (size_t)(i * MBS + mt * 128) * CIN + c0;
    const uint16_t* gb = wt + (size_t)(c_sigma[i][k] * UQ + ut * 128) * CIN + c0;
    uint16_t* la = lds[buf][0];
    uint16_t* lb = lds[buf][1];
#pragma unroll
    for (int ch = 0; ch < 4; ++ch) {
      int e  = ch * 256 + tid;   // 16B chunk id, 0..1023
      int r  = e >> 3;           // tile row 0..127
      int ce = (e & 7) * 8;      // col offset in elements
      __builtin_amdgcn_global_load_lds(
          (const __attribute__((address_space(1))) uint32_t*)(ga + (size_t)r * CIN + ce),
          (__attribute__((address_space(3))) uint32_t*)(la + e * 8), 16, 0, 0);
      __builtin_amdgcn_global_load_lds(
          (const __attribute__((address_space(1))) uint32_t*)(gb + (size_t)r * CIN + ce),
          (__attribute__((address_space(3))) uint32_t*)(lb + e * 8), 16, 0, 0);
    }
  };

  auto compute = [&](int buf) {
    const uint16_t* la = lds[buf][0];
    const uint16_t* lb = lds[buf][1];
    const int ar = wr * 64 + (lane & 15);
    const int br = wc * 64 + (lane & 15);
    const int kc = (lane >> 4) * 8;
#pragma unroll
    for (int kk = 0; kk < 2; ++kk) {
      bf16x8 af[4], bf[4];
#pragma unroll
      for (int f = 0; f < 4; ++f)
        af[f] = *(const bf16x8*)(la + (ar + f * 16) * 64 + kk * 32 + kc);
#pragma unroll
      for (int f = 0; f < 4; ++f)
        bf[f] = *(const bf16x8*)(lb + (br + f * 16) * 64 + kk * 32 + kc);
#pragma unroll
      for (int fm = 0; fm < 4; ++fm)
#pragma unroll
        for (int fn = 0; fn < 4; ++fn)
          acc[fm][fn] = __builtin_amdgcn_mfma_f32_16x16x32_bf16(
              af[fm], bf[fn], acc[fm][fn], 0, 0, 0);
    }
  };

  stage(0, 0);
  __syncthreads();
  for (int t = 0; t < 128; ++t) {
    const int buf = t & 1;
    if (t < 127) stage(t + 1, buf ^ 1);
    compute(buf);
    __syncthreads();
  }

  // epilogue: bias + store (D: col = lane&15, row = (lane>>4)*4 + r)
  const int row0 = k * MBS + mt * 128 + wr * 64;
  const int col0 = ut * 128 + wc * 64;
#pragma unroll
  for (int fn = 0; fn < 4; ++fn) {
    const int col = col0 + fn * 16 + (lane & 15);
    const float bv = bias[k * UQ + col];
#pragma unroll
    for (int fm = 0; fm < 4; ++fm) {
      const int r0 = row0 + fm * 16 + (lane >> 4) * 4;
#pragma unroll
      for (int r = 0; r < 4; ++r)
        out[(size_t)(r0 + r) * UQ + col] = acc[fm][fn][r] + bv;
    }
  }
}

// Fallback (ws too small): correct fp32 path, slow.
__global__ void ga_naive(const float* __restrict__ x, const float* __restrict__ w,
                         const float* __restrict__ bias, float* __restrict__ out) {
  int col = blockIdx.x * 256 + threadIdx.x;  // 0..1023
  int row = blockIdx.y;                       // 0..4095
  int k = row >> 9, m = row & 511;
  float acc = bias[k * UQ + col];
  for (int i = 0; i < 8; ++i) {
    int j = c_sigma[i][k];
    float s = (float)c_sg[i][k];
    const float* xr = x + (size_t)(i * MBS + m) * CIN;
    const float* wc = w + (size_t)j * UQ + col;
    float a = 0.f;
    for (int c = 0; c < CIN; ++c) a = fmaf(xr[c], wc[(size_t)c * (NBL * UQ)], a);
    acc = fmaf(s, a, acc);
  }
  out[(size_t)row * UQ + col] = acc;
}

extern "C" void kernel_launch(void* const* d_in, const int* in_sizes, int n_in,
                              void* d_out, int out_size, void* d_ws, size_t ws_size,
                              hipStream_t stream) {
  const float* x    = (const float*)d_in[0];   // 4096*1024
  const float* W    = (const float*)d_in[1];   // 1024*8192
  const float* bias = (const float*)d_in[2];   // 8192
  float* out = (float*)d_out;                  // 4096*1024

  const size_t need = 32u * 1024u * 1024u;     // X+ 8MB, X- 8MB, Wt 16MB
  if (ws_size < need) {
    ga_naive<<<dim3(4, 4096), dim3(256), 0, stream>>>(x, W, bias, out);
    return;
  }

  uint16_t* xp = (uint16_t*)d_ws;
  uint16_t* xn = xp + 4194304;
  uint16_t* wt = xn + 4194304;

  cvt_x_kernel<<<dim3(2048), dim3(256), 0, stream>>>(
      (const float4*)x, (uint4*)xp, (uint4*)xn);
  cvt_w_kernel<<<dim3(256, 32), dim3(256), 0, stream>>>(W, wt);
  ga_gemm<<<dim3(256), dim3(256), 0, stream>>>(xp, xn, wt, bias, out);
}

// Round 3
// 106.413 us; speedup vs baseline: 1.3589x; 1.3589x over previous
//
#include <hip/hip_runtime.h>
#include <stdint.h>

#define NBL 8
#define MBS 512   // rows per blade
#define CIN 1024  // K per blade block
#define UQ  1024  // output cols per blade

// sigma[i][k]: j such that blade_i * blade_j = sign * blade_k ; sg[i][k] = sign
__device__ __constant__ int c_sigma[8][8] = {
  {0,1,2,3,4,5,6,7},
  {1,0,4,5,2,3,7,6},
  {2,4,0,6,1,7,3,5},
  {3,5,6,0,7,1,2,4},
  {4,2,1,7,0,6,5,3},
  {5,3,7,1,6,0,4,2},
  {6,7,3,2,5,4,0,1},
  {7,6,5,4,3,2,1,0},
};
__device__ __constant__ int c_sg[8][8] = {
  { 1, 1, 1, 1, 1, 1, 1, 1},
  { 1, 1, 1, 1, 1, 1, 1, 1},
  { 1,-1, 1, 1,-1,-1, 1,-1},
  { 1,-1,-1, 1, 1,-1,-1, 1},
  {-1, 1,-1,-1, 1, 1,-1, 1},
  {-1, 1, 1,-1,-1, 1, 1,-1},
  {-1,-1, 1,-1, 1,-1, 1, 1},
  {-1,-1, 1,-1, 1,-1, 1, 1},
};

typedef short bf16x8 __attribute__((ext_vector_type(8)));
typedef float f32x4 __attribute__((ext_vector_type(4)));

__device__ __forceinline__ uint32_t f2bf(float f) {
  uint32_t u = __float_as_uint(f);
  return (u + 0x7fffu + ((u >> 16) & 1u)) >> 16;  // RNE
}
__device__ __forceinline__ uint32_t pk2(float lo, float hi) {
  return f2bf(lo) | (f2bf(hi) << 16);
}

// x (4096x1024 f32) -> X+ bf16 and X- bf16 (sign flip = xor 0x8000, RNE-symmetric)
__global__ void cvt_x_kernel(const float4* __restrict__ x,
                             uint4* __restrict__ xp, uint4* __restrict__ xn) {
  int idx = blockIdx.x * blockDim.x + threadIdx.x;  // 524288 threads, 8 floats each
  float4 a = x[2 * idx];
  float4 b = x[2 * idx + 1];
  uint4 p;
  p.x = pk2(a.x, a.y); p.y = pk2(a.z, a.w);
  p.z = pk2(b.x, b.y); p.w = pk2(b.z, b.w);
  uint4 n;
  n.x = p.x ^ 0x80008000u; n.y = p.y ^ 0x80008000u;
  n.z = p.z ^ 0x80008000u; n.w = p.w ^ 0x80008000u;
  xp[idx] = p;
  xn[idx] = n;
}

// W [1024][8192] f32 -> Wt [8192][1024] bf16 (transpose so B-tiles are K-contiguous)
__global__ void cvt_w_kernel(const float* __restrict__ w, uint16_t* __restrict__ wt) {
  __shared__ float tile[32][33];
  int tx = threadIdx.x & 31, ty = threadIdx.x >> 5;  // 32x8
  int n0 = blockIdx.x * 32;   // 0..8191 over n
  int c0 = blockIdx.y * 32;   // 0..1023 over c
#pragma unroll
  for (int r = 0; r < 4; ++r) {
    int c = c0 + ty + r * 8;
    tile[ty + r * 8][tx] = w[(size_t)c * 8192 + n0 + tx];
  }
  __syncthreads();
#pragma unroll
  for (int r = 0; r < 4; ++r) {
    int n = n0 + ty + r * 8;
    wt[(size_t)n * 1024 + c0 + tx] = (uint16_t)f2bf(tile[tx][ty + r * 8]);
  }
}

// out[r][c] = bias[(r>>9)*1024 + c]  (prefill; GEMM atomically accumulates)
__global__ void bias_fill(const float* __restrict__ bias, float4* __restrict__ out) {
  int idx = blockIdx.x * 256 + threadIdx.x;  // 1M float4
  int row = idx >> 8;                        // 256 float4 per row
  int c4 = idx & 255;
  int k = row >> 9;
  out[idx] = ((const float4*)(bias + k * UQ))[c4];
}

// Main GEMM, split-K=2: block (s, k, mt, ut) accumulates K-steps t in
// [s*64, s*64+64) into out via atomicAdd. LDS tiles XOR-swizzled (T2):
// LDS chunk (r,c) holds global chunk (r, c^(r&7)); reads apply same XOR.
__global__ __launch_bounds__(256, 2) void ga_gemm(
    const uint16_t* __restrict__ xp, const uint16_t* __restrict__ xn,
    const uint16_t* __restrict__ wt,
    float* __restrict__ out) {
  __shared__ uint16_t lds[2][2][128 * 64];  // [buf][A/B][128 rows][64 k] = 64 KB

  const int tid  = threadIdx.x;
  const int bid  = blockIdx.x;
  const int s    = bid >> 8;          // K-split 0/1
  const int k    = (bid >> 5) & 7;
  const int mt   = (bid >> 3) & 3;
  const int ut   = bid & 7;
  const int lane = tid & 63;
  const int wid  = tid >> 6;
  const int wr   = wid >> 1, wc = wid & 1;  // 2x2 waves, each 64x64 out

  f32x4 acc[4][4];
  const f32x4 z = {0.f, 0.f, 0.f, 0.f};
#pragma unroll
  for (int a = 0; a < 4; ++a)
#pragma unroll
    for (int b = 0; b < 4; ++b) acc[a][b] = z;

  auto stage = [&](int t, int buf) {
    const int i  = t >> 4;             // i-block (K block of 1024)
    const int c0 = (t & 15) << 6;      // k offset within block
    const uint16_t* ga = ((c_sg[i][k] > 0) ? xp : xn) +
                         (size_t)(i * MBS + mt * 128) * CIN + c0;
    const uint16_t* gb = wt + (size_t)(c_sigma[i][k] * UQ + ut * 128) * CIN + c0;
    uint16_t* la = lds[buf][0];
    uint16_t* lb = lds[buf][1];
#pragma unroll
    for (int ch = 0; ch < 4; ++ch) {
      int e  = ch * 256 + tid;   // 16B chunk id, 0..1023
      int r  = e >> 3;           // tile row 0..127
      int c  = e & 7;            // chunk within row
      int cs = c ^ (r & 7);      // pre-swizzled source chunk (rule #21)
      __builtin_amdgcn_global_load_lds(
          (const __attribute__((address_space(1))) uint32_t*)(ga + (size_t)r * CIN + cs * 8),
          (__attribute__((address_space(3))) uint32_t*)(la + e * 8), 16, 0, 0);
      __builtin_amdgcn_global_load_lds(
          (const __attribute__((address_space(1))) uint32_t*)(gb + (size_t)r * CIN + cs * 8),
          (__attribute__((address_space(3))) uint32_t*)(lb + e * 8), 16, 0, 0);
    }
  };

  auto compute = [&](int buf) {
    const uint16_t* la = lds[buf][0];
    const uint16_t* lb = lds[buf][1];
    const int ar = wr * 64 + (lane & 15);
    const int br = wc * 64 + (lane & 15);
    const int cx = lane & 7;            // row&7 for all frags (f*16 ≡ 0 mod 8)
#pragma unroll
    for (int kk = 0; kk < 2; ++kk) {
      const int gc = kk * 4 + (lane >> 4);   // global chunk 0..7
      const int sc = (gc ^ cx) * 8;          // swizzled element offset in row
      bf16x8 af[4], bf[4];
#pragma unroll
      for (int f = 0; f < 4; ++f)
        af[f] = *(const bf16x8*)(la + (ar + f * 16) * 64 + sc);
#pragma unroll
      for (int f = 0; f < 4; ++f)
        bf[f] = *(const bf16x8*)(lb + (br + f * 16) * 64 + sc);
#pragma unroll
      for (int fm = 0; fm < 4; ++fm)
#pragma unroll
        for (int fn = 0; fn < 4; ++fn)
          acc[fm][fn] = __builtin_amdgcn_mfma_f32_16x16x32_bf16(
              af[fm], bf[fn], acc[fm][fn], 0, 0, 0);
    }
  };

  const int t0 = s * 64;
  stage(t0, 0);
  __syncthreads();
  for (int tt = 0; tt < 64; ++tt) {
    const int buf = tt & 1;
    if (tt < 63) stage(t0 + tt + 1, buf ^ 1);
    compute(buf);
    __syncthreads();
  }

  // epilogue: atomic accumulate (D: col = lane&15, row = (lane>>4)*4 + r)
  const int row0 = k * MBS + mt * 128 + wr * 64;
  const int col0 = ut * 128 + wc * 64;
#pragma unroll
  for (int fn = 0; fn < 4; ++fn) {
    const int col = col0 + fn * 16 + (lane & 15);
#pragma unroll
    for (int fm = 0; fm < 4; ++fm) {
      const int r0 = row0 + fm * 16 + (lane >> 4) * 4;
#pragma unroll
      for (int r = 0; r < 4; ++r)
        unsafeAtomicAdd(&out[(size_t)(r0 + r) * UQ + col], acc[fm][fn][r]);
    }
  }
}

// Fallback (ws too small): correct fp32 path, slow.
__global__ void ga_naive(const float* __restrict__ x, const float* __restrict__ w,
                         const float* __restrict__ bias, float* __restrict__ out) {
  int col = blockIdx.x * 256 + threadIdx.x;  // 0..1023
  int row = blockIdx.y;                       // 0..4095
  int k = row >> 9, m = row & 511;
  float acc = bias[k * UQ + col];
  for (int i = 0; i < 8; ++i) {
    int j = c_sigma[i][k];
    float s = (float)c_sg[i][k];
    const float* xr = x + (size_t)(i * MBS + m) * CIN;
    const float* wc = w + (size_t)j * UQ + col;
    float a = 0.f;
    for (int c = 0; c < CIN; ++c) a = fmaf(xr[c], wc[(size_t)c * (NBL * UQ)], a);
    acc = fmaf(s, a, acc);
  }
  out[(size_t)row * UQ + col] = acc;
}

extern "C" void kernel_launch(void* const* d_in, const int* in_sizes, int n_in,
                              void* d_out, int out_size, void* d_ws, size_t ws_size,
                              hipStream_t stream) {
  const float* x    = (const float*)d_in[0];   // 4096*1024
  const float* W    = (const float*)d_in[1];   // 1024*8192
  const float* bias = (const float*)d_in[2];   // 8192
  float* out = (float*)d_out;                  // 4096*1024

  const size_t need = 32u * 1024u * 1024u;     // X+ 8MB, X- 8MB, Wt 16MB
  if (ws_size < need) {
    ga_naive<<<dim3(4, 4096), dim3(256), 0, stream>>>(x, W, bias, out);
    return;
  }

  uint16_t* xp = (uint16_t*)d_ws;
  uint16_t* xn = xp + 4194304;
  uint16_t* wt = xn + 4194304;

  cvt_x_kernel<<<dim3(2048), dim3(256), 0, stream>>>(
      (const float4*)x, (uint4*)xp, (uint4*)xn);
  cvt_w_kernel<<<dim3(256, 32), dim3(256), 0, stream>>>(W, wt);
  bias_fill<<<dim3(4096), dim3(256), 0, stream>>>(bias, (float4*)out);
  ga_gemm<<<dim3(512), dim3(256), 0, stream>>>(xp, xn, wt, out);
}